// Round 3
// baseline (167.001 us; speedup 1.0000x reference)
//
#include <hip/hip_runtime.h>
#include <hip/hip_bf16.h>

typedef short short8 __attribute__((ext_vector_type(8)));
typedef float f32x4 __attribute__((ext_vector_type(4)));

// Workspace byte offsets
#define WF_OFF  0u        // bf16 wfrag[t=27][ot=2][lane=64][j=8] = 55296 B
#define RWB_OFF 55296u    // f32 rw_sum[b]*bias_sum[o] : [8][32] = 1024 B
#define RWS_OFF 56320u    // f32 rw_sum[8] = 32 B

__device__ __forceinline__ unsigned bf16rne(float f) {
    unsigned u = __float_as_uint(f);
    return (u + 0x7FFFu + ((u >> 16) & 1u)) >> 16;
}

// ---------------------------------------------------------------------------
// Prep: wfrag in MFMA A-operand layout; rwb_bias; rw_sum.
// A-frag (16x16x32 bf16): lane l holds A[m = l&15][k = 8*(l>>4)+j], j=0..7.
// m = o (within o-tile), k = c.  wfrag elem idx = ((t*2+ot)*64 + l)*8 + j.
// ---------------------------------------------------------------------------
__global__ void condconv_prep(const float* __restrict__ rw,      // [8,8]
                              const float* __restrict__ weight,  // [8,32,32,27]
                              const float* __restrict__ bias,    // [8,32]
                              char* __restrict__ ws) {
    int i = blockIdx.x * 256 + threadIdx.x;
    if (i < 27648) {
        int t   = i >> 10;
        int rem = i & 1023;
        int ot  = rem >> 9;
        int l   = (rem >> 3) & 63;
        int j   = rem & 7;
        int o   = ot * 16 + (l & 15);
        int c   = 8 * (l >> 4) + j;
        float s = 0.f;
#pragma unroll
        for (int e = 0; e < 8; ++e) s += weight[((e * 32 + o) * 32 + c) * 27 + t];
        ((unsigned short*)(ws + WF_OFF))[i] = (unsigned short)bf16rne(s);
    } else if (i < 27904) {
        int k = i - 27648;
        int b = k >> 5, o = k & 31;
        float rs = 0.f, bs = 0.f;
#pragma unroll
        for (int e = 0; e < 8; ++e) { rs += rw[b * 8 + e]; bs += bias[e * 32 + o]; }
        ((float*)(ws + RWB_OFF))[k] = rs * bs;
        if (o == 0) ((float*)(ws + RWS_OFF))[b] = rs;
    }
}

// ---------------------------------------------------------------------------
// Fused cast+conv: implicit GEMM, bf16 MFMA 16x16x32, staging directly from
// fp32 x with in-LDS transpose.
// Block = (b, z, 4 y-rows); 4 waves; wave w owns x-chunk [16w,16w+16), all 32 o.
// LDS x-tile: [18 rows = 3z' x 6y'][66 x (halo)][32 c] bf16 = 76032 B.
// Compute: y'-sharing -> 54 ds_read_b128/wave, weights in regs per dz.
// ---------------------------------------------------------------------------
__global__ __launch_bounds__(256, 2) void condconv_fused(
        const float* __restrict__ x,     // [8,32,16,64,64] fp32
        const char* __restrict__ wf,     // ws + WF_OFF
        const float* __restrict__ rwbias,
        const float* __restrict__ rwsum,
        float* __restrict__ out) {
    __shared__ uint4 smem4[4752];        // 76032 B
    char* smem = (char*)smem4;

    const int tid  = threadIdx.x;
    const int wv   = tid >> 6;
    const int lane = tid & 63;
    const int n    = lane & 15;
    const int quad = lane >> 4;
    const int y0   = blockIdx.x * 4;
    const int z    = blockIdx.y;
    const int b    = blockIdx.z;
    const int xn   = wv * 16 + n;

    // zero halo columns (x-index 0 and 65) for all 18 rows
    if (tid < 144) {
        int row = tid >> 3, rem = tid & 7;
        int side = rem >> 2, q = rem & 3;
        *(uint4*)(smem + (row * 66 + side * 65) * 64 + q * 16) = make_uint4(0, 0, 0, 0);
    }

    // ---- stage: fp32 x -> bf16 LDS [row][x][c], transposing c to innermost ----
    // 2304 sets = 18 rows x 8 c-quads x 16 x4-groups; 9 per thread.
    const float* xb = x + (size_t)b * (32 * 16 * 64 * 64);
#pragma unroll
    for (int i = 0; i < 9; ++i) {
        const int s   = tid + i * 256;
        const int row = s >> 7;          // 0..17
        const int rem = s & 127;
        const int c4  = rem & 7;         // c-quad: c = 4*c4 .. 4*c4+3
        const int x4  = rem >> 3;        // 0..15 : gx = 4*x4 .. 4*x4+3
        const int zp  = row / 6, yp = row - zp * 6;
        const int gz  = z + zp - 1, gy = y0 + yp - 1;
        float4 v0 = {0, 0, 0, 0}, v1 = v0, v2 = v0, v3 = v0;
        if ((unsigned)gz < 16u && (unsigned)gy < 64u) {
            const float* p = xb + (((size_t)(4 * c4) * 16 + gz) * 64 + gy) * 64 + 4 * x4;
            v0 = *(const float4*)(p);
            v1 = *(const float4*)(p + 65536);
            v2 = *(const float4*)(p + 131072);
            v3 = *(const float4*)(p + 196608);
        }
        const float a0[4] = {v0.x, v0.y, v0.z, v0.w};
        const float a1[4] = {v1.x, v1.y, v1.z, v1.w};
        const float a2[4] = {v2.x, v2.y, v2.z, v2.w};
        const float a3[4] = {v3.x, v3.y, v3.z, v3.w};
#pragma unroll
        for (int xi = 0; xi < 4; ++xi) {
            union { __hip_bfloat162 h2[2]; uint2 u; } g;
            g.h2[0] = __float22bfloat162_rn(make_float2(a0[xi], a1[xi]));
            g.h2[1] = __float22bfloat162_rn(make_float2(a2[xi], a3[xi]));
            // LDS byte addr: x-index = 4*x4+xi+1 (halo shift), c-offset 8*c4
            *(uint2*)(smem + (row * 66 + 4 * x4 + xi + 1) * 64 + c4 * 8) = g.u;
        }
    }
    __syncthreads();

    // ---- compute ----
    f32x4 acc[2][4] = {};                // [o-tile][y-row r]
    const char* wb = wf + lane * 16;

#pragma unroll
    for (int dz = 0; dz < 3; ++dz) {
        short8 wreg[9][2];
#pragma unroll
        for (int tt = 0; tt < 9; ++tt) {
            wreg[tt][0] = *(const short8*)(wb + ((dz * 9 + tt) * 2 + 0) * 1024);
            wreg[tt][1] = *(const short8*)(wb + ((dz * 9 + tt) * 2 + 1) * 1024);
        }
#pragma unroll
        for (int yq = 0; yq < 6; ++yq) {
#pragma unroll
            for (int dx = 0; dx < 3; ++dx) {
                short8 xf = *(const short8*)(
                    smem + ((dz * 6 + yq) * 66 + xn + dx) * 64 + quad * 16);
#pragma unroll
                for (int dy = 0; dy < 3; ++dy) {
                    const int r = yq - dy;
                    if (r >= 0 && r < 4) {
                        acc[0][r] = __builtin_amdgcn_mfma_f32_16x16x32_bf16(
                            wreg[dy * 3 + dx][0], xf, acc[0][r], 0, 0, 0);
                        acc[1][r] = __builtin_amdgcn_mfma_f32_16x16x32_bf16(
                            wreg[dy * 3 + dx][1], xf, acc[1][r], 0, 0, 0);
                    }
                }
            }
        }
    }

    // ---- epilogue: out = rw_sum[b]*acc + rw_sum[b]*bias_sum[o] ----
    const float rwb = rwsum[b];
#pragma unroll
    for (int ot = 0; ot < 2; ++ot)
#pragma unroll
        for (int reg = 0; reg < 4; ++reg) {
            const int o = ot * 16 + quad * 4 + reg;   // D row = quad*4+reg
            const float bb = rwbias[b * 32 + o];
            const size_t obase = ((size_t)(b * 32 + o) * 16 + z) * 64;
#pragma unroll
            for (int r = 0; r < 4; ++r)
                out[(obase + y0 + r) * 64 + xn] = rwb * acc[ot][r][reg] + bb;
        }
}

// ---------------------------------------------------------------------------
extern "C" void kernel_launch(void* const* d_in, const int* in_sizes, int n_in,
                              void* d_out, int out_size, void* d_ws, size_t ws_size,
                              hipStream_t stream) {
    const float* x      = (const float*)d_in[0];  // [8,32,16,64,64]
    const float* rw     = (const float*)d_in[1];  // [8,8]
    const float* weight = (const float*)d_in[2];  // [8,32,32,27]
    const float* bias   = (const float*)d_in[3];  // [8,32]
    float* out = (float*)d_out;
    char*  ws  = (char*)d_ws;

    condconv_prep<<<109, 256, 0, stream>>>(rw, weight, bias, ws);
    condconv_fused<<<dim3(16, 16, 8), 256, 0, stream>>>(
        x, ws + WF_OFF,
        (const float*)(ws + RWB_OFF), (const float*)(ws + RWS_OFF), out);
}

// Round 4
// 152.563 us; speedup vs baseline: 1.0946x; 1.0946x over previous
//
#include <hip/hip_runtime.h>
#include <hip/hip_bf16.h>

typedef short short8 __attribute__((ext_vector_type(8)));
typedef short short4v __attribute__((ext_vector_type(4)));
typedef float f32x4 __attribute__((ext_vector_type(4)));

// Workspace byte offsets
#define WF_OFF  0u        // bf16 wfrag[t=27][ot=2][lane=64][j=8] = 55296 B
#define RWB_OFF 55296u    // f32 rw_sum[b]*bias_sum[o] : [8][32] = 1024 B
#define RWS_OFF 56320u    // f32 rw_sum[8] = 32 B

// LDS x-plane layout: [yp 0..5][X 0..65][c-slot], x-stride 72 B (64 data + 8 pad)
// 72 B stride => staging ds_write_b64 spreads over all 32 banks (2-way, free).
#define XS 72
#define RS (66 * XS)      // 4752 B per (yp) row
#define PLANE (6 * RS)    // 28512 B total LDS

__device__ __forceinline__ unsigned bf16rne(float f) {
    unsigned u = __float_as_uint(f);
    return (u + 0x7FFFu + ((u >> 16) & 1u)) >> 16;
}

// ---------------------------------------------------------------------------
// Prep: wfrag in MFMA A-operand layout; rwb_bias; rw_sum.
// A-frag (16x16x32 bf16): lane l holds A[m = l&15][k = 8*(l>>4)+j], j=0..7.
// m = o (within o-tile), k = c.  wfrag elem idx = ((t*2+ot)*64 + l)*8 + j.
// ---------------------------------------------------------------------------
__global__ void condconv_prep(const float* __restrict__ rw,      // [8,8]
                              const float* __restrict__ weight,  // [8,32,32,27]
                              const float* __restrict__ bias,    // [8,32]
                              char* __restrict__ ws) {
    int i = blockIdx.x * 256 + threadIdx.x;
    if (i < 27648) {
        int t   = i >> 10;
        int rem = i & 1023;
        int ot  = rem >> 9;
        int l   = (rem >> 3) & 63;
        int j   = rem & 7;
        int o   = ot * 16 + (l & 15);
        int c   = 8 * (l >> 4) + j;
        float s = 0.f;
#pragma unroll
        for (int e = 0; e < 8; ++e) s += weight[((e * 32 + o) * 32 + c) * 27 + t];
        ((unsigned short*)(ws + WF_OFF))[i] = (unsigned short)bf16rne(s);
    } else if (i < 27904) {
        int k = i - 27648;
        int b = k >> 5, o = k & 31;
        float rs = 0.f, bs = 0.f;
#pragma unroll
        for (int e = 0; e < 8; ++e) { rs += rw[b * 8 + e]; bs += bias[e * 32 + o]; }
        ((float*)(ws + RWB_OFF))[k] = rs * bs;
        if (o == 0) ((float*)(ws + RWS_OFF))[b] = rs;
    }
}

// ---------------------------------------------------------------------------
// Fused cast+conv, z-plane phased.
// Block = (b, z, 4 y-rows); 4 waves; wave w owns x-chunk [16w,16w+16), all 32 o.
// Per dz-phase: stage plane z+dz-1 (fp32 -> bf16, c innermost) into 28.5 KB LDS,
// then 18 ds-frag reads + 72 MFMA per wave.  Swizzle: 16B c-granule q ^= (X&3).
// ---------------------------------------------------------------------------
__global__ __launch_bounds__(256, 3) void condconv_fused(
        const float* __restrict__ x,     // [8,32,16,64,64] fp32
        const char* __restrict__ wf,     // ws + WF_OFF
        const float* __restrict__ rwbias,
        const float* __restrict__ rwsum,
        float* __restrict__ out) {
    __shared__ __align__(16) char smem[PLANE];

    const int tid  = threadIdx.x;
    const int wv   = tid >> 6;
    const int lane = tid & 63;
    const int n    = lane & 15;
    const int quad = lane >> 4;
    const int y0   = blockIdx.x * 4;
    const int z    = blockIdx.y;
    const int b    = blockIdx.z;
    const int xn   = wv * 16 + n;

    // zero halo columns X=0 and X=65 (64 B of c each, 6 rows) — never overwritten
    if (tid < 48) {
        int yp = tid >> 3, side = (tid >> 2) & 1, q = tid & 3;
        *(uint4*)(smem + yp * RS + side * 65 * XS + q * 16) = make_uint4(0, 0, 0, 0);
    }

    f32x4 acc[2][4] = {};                          // [o-tile][y-row r]
    const float* xb = x + (size_t)b * 2097152;     // 32*16*64*64
    const char* wbase = wf + lane * 16;

#pragma unroll
    for (int dz = 0; dz < 3; ++dz) {
        const int gz = z + dz - 1;
        const bool gzok = (unsigned)gz < 16u;

        __syncthreads();   // previous phase's reads done (also orders halo zero)
        if (gzok) {
            // stage: 768 quad-sets = 6 yp x 8 c4 x 16 x4 ; 3 sets/thread
#pragma unroll
            for (int it = 0; it < 3; ++it) {
                const int s  = it * 256 + tid;
                const int x4 = s & 15;
                const int c4 = (s >> 4) & 7;       // c = 4*c4 .. 4*c4+3
                const int yp = s >> 7;             // wave-uniform
                const int gy = y0 + yp - 1;
                float4 v0 = {0, 0, 0, 0}, v1 = v0, v2 = v0, v3 = v0;
                if ((unsigned)gy < 64u) {
                    const float* p = xb + (size_t)c4 * 262144 + gz * 4096 + gy * 64 + 4 * x4;
                    v0 = *(const float4*)(p);
                    v1 = *(const float4*)(p + 65536);
                    v2 = *(const float4*)(p + 131072);
                    v3 = *(const float4*)(p + 196608);
                }
                const float a0[4] = {v0.x, v0.y, v0.z, v0.w};
                const float a1[4] = {v1.x, v1.y, v1.z, v1.w};
                const float a2[4] = {v2.x, v2.y, v2.z, v2.w};
                const float a3[4] = {v3.x, v3.y, v3.z, v3.w};
#pragma unroll
                for (int xi = 0; xi < 4; ++xi) {
                    union { __hip_bfloat162 h2[2]; uint2 u; } g;
                    g.h2[0] = __float22bfloat162_rn(make_float2(a0[xi], a1[xi]));
                    g.h2[1] = __float22bfloat162_rn(make_float2(a2[xi], a3[xi]));
                    const int X = 4 * x4 + xi + 1;
                    // c-slot swizzled at 16B granule: slot8' = c4 ^ ((X&3)<<1)
                    *(uint2*)(smem + yp * RS + X * XS + ((c4 ^ ((X & 3) << 1)) << 3)) = g.u;
                }
            }
        }
        __syncthreads();

        if (gzok) {
            short8 wreg[18];                       // this dz's 9 taps x 2 o-tiles
            const char* wp = wbase + dz * 18432;
#pragma unroll
            for (int t = 0; t < 18; ++t) wreg[t] = *(const short8*)(wp + t * 1024);
#pragma unroll
            for (int yq = 0; yq < 6; ++yq) {
#pragma unroll
                for (int dx = 0; dx < 3; ++dx) {
                    const int X = xn + dx;
                    const char* rp = smem + yq * RS + X * XS + ((quad ^ (X & 3)) << 4);
                    union { short8 v; short4v h[2]; } xf;
                    xf.h[0] = *(const short4v*)rp;
                    xf.h[1] = *(const short4v*)(rp + 8);
#pragma unroll
                    for (int dy = 0; dy < 3; ++dy) {
                        const int r = yq - dy;
                        if (r >= 0 && r < 4) {
                            acc[0][r] = __builtin_amdgcn_mfma_f32_16x16x32_bf16(
                                wreg[(dy * 3 + dx) * 2 + 0], xf.v, acc[0][r], 0, 0, 0);
                            acc[1][r] = __builtin_amdgcn_mfma_f32_16x16x32_bf16(
                                wreg[(dy * 3 + dx) * 2 + 1], xf.v, acc[1][r], 0, 0, 0);
                        }
                    }
                }
            }
        }
    }

    // ---- epilogue: out = rw_sum[b]*acc + rw_sum[b]*bias_sum[o] ----
    const float rwb = rwsum[b];
#pragma unroll
    for (int ot = 0; ot < 2; ++ot)
#pragma unroll
        for (int reg = 0; reg < 4; ++reg) {
            const int o = ot * 16 + quad * 4 + reg;   // D row = quad*4+reg
            const float bb = rwbias[b * 32 + o];
            const size_t obase = ((size_t)(b * 32 + o) * 16 + z) * 64;
#pragma unroll
            for (int r = 0; r < 4; ++r)
                out[(obase + y0 + r) * 64 + xn] = rwb * acc[ot][r][reg] + bb;
        }
}

// ---------------------------------------------------------------------------
extern "C" void kernel_launch(void* const* d_in, const int* in_sizes, int n_in,
                              void* d_out, int out_size, void* d_ws, size_t ws_size,
                              hipStream_t stream) {
    const float* x      = (const float*)d_in[0];  // [8,32,16,64,64]
    const float* rw     = (const float*)d_in[1];  // [8,8]
    const float* weight = (const float*)d_in[2];  // [8,32,32,27]
    const float* bias   = (const float*)d_in[3];  // [8,32]
    float* out = (float*)d_out;
    char*  ws  = (char*)d_ws;

    condconv_prep<<<109, 256, 0, stream>>>(rw, weight, bias, ws);
    condconv_fused<<<dim3(16, 16, 8), 256, 0, stream>>>(
        x, ws + WF_OFF,
        (const float*)(ws + RWB_OFF), (const float*)(ws + RWS_OFF), out);
}

// Round 5
// 150.030 us; speedup vs baseline: 1.1131x; 1.0169x over previous
//
#include <hip/hip_runtime.h>
#include <hip/hip_bf16.h>

typedef short short8 __attribute__((ext_vector_type(8)));
typedef short short4v __attribute__((ext_vector_type(4)));
typedef float f32x4 __attribute__((ext_vector_type(4)));

// Workspace byte offsets
#define WF_OFF  0u        // bf16 wfrag[t=27][ot=2][lane=64][j=8] = 55296 B
#define RWB_OFF 55296u    // f32 rw_sum[b]*bias_sum[o] : [8][32] = 1024 B
#define RWS_OFF 56320u    // f32 rw_sum[8] = 32 B

// LDS x-plane: [yp 0..9][X 0..65][c-slot], x-stride 72 B (64 data + 8 pad).
// 8 B c-slots swizzled: slot' = slot ^ ((X>>2)&7)  -> staging writes exactly
// 2 lanes/bank (free), frag reads ~2-way.
#define XS 72
#define RS (66 * XS)       // 4752 B per yp row
#define PLANE (10 * RS)    // 47520 B total LDS

__device__ __forceinline__ unsigned bf16rne(float f) {
    unsigned u = __float_as_uint(f);
    return (u + 0x7FFFu + ((u >> 16) & 1u)) >> 16;
}

// ---------------------------------------------------------------------------
// Prep: wfrag in MFMA A-operand layout; rwb_bias; rw_sum.
// A-frag (16x16x32 bf16): lane l holds A[m = l&15][k = 8*(l>>4)+j], j=0..7.
// m = o (within o-tile), k = c.  wfrag elem idx = ((t*2+ot)*64 + l)*8 + j.
// ---------------------------------------------------------------------------
__global__ void condconv_prep(const float* __restrict__ rw,      // [8,8]
                              const float* __restrict__ weight,  // [8,32,32,27]
                              const float* __restrict__ bias,    // [8,32]
                              char* __restrict__ ws) {
    int i = blockIdx.x * 256 + threadIdx.x;
    if (i < 27648) {
        int t   = i >> 10;
        int rem = i & 1023;
        int ot  = rem >> 9;
        int l   = (rem >> 3) & 63;
        int j   = rem & 7;
        int o   = ot * 16 + (l & 15);
        int c   = 8 * (l >> 4) + j;
        float s = 0.f;
#pragma unroll
        for (int e = 0; e < 8; ++e) s += weight[((e * 32 + o) * 32 + c) * 27 + t];
        ((unsigned short*)(ws + WF_OFF))[i] = (unsigned short)bf16rne(s);
    } else if (i < 27904) {
        int k = i - 27648;
        int b = k >> 5, o = k & 31;
        float rs = 0.f, bs = 0.f;
#pragma unroll
        for (int e = 0; e < 8; ++e) { rs += rw[b * 8 + e]; bs += bias[e * 32 + o]; }
        ((float*)(ws + RWB_OFF))[k] = rs * bs;
        if (o == 0) ((float*)(ws + RWS_OFF))[b] = rs;
    }
}

// ---------------------------------------------------------------------------
// Fused cast+conv, z-plane phased, y-tile = 8.
// Block = (b, z, 8 y-rows); 4 waves; wave w owns x-chunk [16w,16w+16), all 32 o.
// Per dz-phase: stage plane z+dz-1 (fp32 -> bf16, c innermost, swizzled) into
// 47.5 KB LDS, then 30 frag reads + 144 MFMA per wave.
// ---------------------------------------------------------------------------
__global__ __launch_bounds__(256, 3) void condconv_fused(
        const float* __restrict__ x,     // [8,32,16,64,64] fp32
        const char* __restrict__ wf,     // ws + WF_OFF
        const float* __restrict__ rwbias,
        const float* __restrict__ rwsum,
        float* __restrict__ out) {
    __shared__ __align__(16) char smem[PLANE];

    const int tid  = threadIdx.x;
    const int wv   = tid >> 6;
    const int lane = tid & 63;
    const int n    = lane & 15;
    const int quad = lane >> 4;
    const int y0   = blockIdx.x * 8;
    const int z    = blockIdx.y;
    const int b    = blockIdx.z;
    const int xn   = wv * 16 + n;

    // zero halo columns X=0 and X=65 (full 64 B c-row, 10 yp rows) — covers any
    // swizzle permutation; never overwritten by staging (X in 1..64).
    if (tid < 80) {
        int yp = tid >> 3, side = (tid >> 2) & 1, q = tid & 3;
        *(uint4*)(smem + yp * RS + side * (65 * XS) + q * 16) = make_uint4(0, 0, 0, 0);
    }

    f32x4 acc[2][8] = {};                          // [o-tile][y-row r]
    const float* xb = x + (size_t)b * 2097152;     // 32*16*64*64
    const char* wbase = wf + lane * 16;

#pragma unroll
    for (int dz = 0; dz < 3; ++dz) {
        const int gz = z + dz - 1;
        const bool gzok = (unsigned)gz < 16u;

        __syncthreads();   // previous phase's reads done (also orders halo zero)
        if (gzok) {
            // stage: 1280 quad-sets = 10 yp x 8 c4 x 16 x4 ; 5 sets/thread
#pragma unroll
            for (int it = 0; it < 5; ++it) {
                const int s  = it * 256 + tid;
                const int x4 = s & 15;
                const int c4 = (s >> 4) & 7;       // c = 4*c4 .. 4*c4+3
                const int yp = s >> 7;             // 0..9, wave-uniform
                const int gy = y0 + yp - 1;
                float4 v0 = {0, 0, 0, 0}, v1 = v0, v2 = v0, v3 = v0;
                if ((unsigned)gy < 64u) {
                    const float* p = xb + (size_t)c4 * 262144 + gz * 4096 + gy * 64 + 4 * x4;
                    v0 = *(const float4*)(p);
                    v1 = *(const float4*)(p + 65536);
                    v2 = *(const float4*)(p + 131072);
                    v3 = *(const float4*)(p + 196608);
                }
                const float a0[4] = {v0.x, v0.y, v0.z, v0.w};
                const float a1[4] = {v1.x, v1.y, v1.z, v1.w};
                const float a2[4] = {v2.x, v2.y, v2.z, v2.w};
                const float a3[4] = {v3.x, v3.y, v3.z, v3.w};
#pragma unroll
                for (int xi = 0; xi < 4; ++xi) {
                    union { __hip_bfloat162 h2[2]; uint2 u; } g;
                    g.h2[0] = __float22bfloat162_rn(make_float2(a0[xi], a1[xi]));
                    g.h2[1] = __float22bfloat162_rn(make_float2(a2[xi], a3[xi]));
                    const int X = 4 * x4 + xi + 1;
                    const int slot = c4 ^ ((X >> 2) & 7);
                    *(uint2*)(smem + yp * RS + X * XS + slot * 8) = g.u;
                }
            }
        }
        __syncthreads();

        if (gzok) {
            short8 wreg[18];                       // this dz's 9 taps x 2 o-tiles
            const char* wp = wbase + dz * 18432;
#pragma unroll
            for (int t = 0; t < 18; ++t) wreg[t] = *(const short8*)(wp + t * 1024);
#pragma unroll
            for (int yq = 0; yq < 10; ++yq) {
#pragma unroll
                for (int dx = 0; dx < 3; ++dx) {
                    const int X = xn + dx;
                    const char* rowp = smem + yq * RS + X * XS;
                    const int s8 = (X >> 2) & 7;
                    union { short8 v; short4v h[2]; } xf;
                    xf.h[0] = *(const short4v*)(rowp + (((2 * quad + 0) ^ s8) << 3));
                    xf.h[1] = *(const short4v*)(rowp + (((2 * quad + 1) ^ s8) << 3));
#pragma unroll
                    for (int dy = 0; dy < 3; ++dy) {
                        const int r = yq - dy;
                        if (r >= 0 && r < 8) {
                            acc[0][r] = __builtin_amdgcn_mfma_f32_16x16x32_bf16(
                                wreg[(dy * 3 + dx) * 2 + 0], xf.v, acc[0][r], 0, 0, 0);
                            acc[1][r] = __builtin_amdgcn_mfma_f32_16x16x32_bf16(
                                wreg[(dy * 3 + dx) * 2 + 1], xf.v, acc[1][r], 0, 0, 0);
                        }
                    }
                }
            }
        }
    }

    // ---- epilogue: out = rw_sum[b]*acc + rw_sum[b]*bias_sum[o] ----
    const float rwb = rwsum[b];
#pragma unroll
    for (int ot = 0; ot < 2; ++ot)
#pragma unroll
        for (int reg = 0; reg < 4; ++reg) {
            const int o = ot * 16 + quad * 4 + reg;   // D row = quad*4+reg
            const float bb = rwbias[b * 32 + o];
            const size_t obase = ((size_t)(b * 32 + o) * 16 + z) * 64;
#pragma unroll
            for (int r = 0; r < 8; ++r)
                out[(obase + y0 + r) * 64 + xn] = rwb * acc[ot][r][reg] + bb;
        }
}

// ---------------------------------------------------------------------------
extern "C" void kernel_launch(void* const* d_in, const int* in_sizes, int n_in,
                              void* d_out, int out_size, void* d_ws, size_t ws_size,
                              hipStream_t stream) {
    const float* x      = (const float*)d_in[0];  // [8,32,16,64,64]
    const float* rw     = (const float*)d_in[1];  // [8,8]
    const float* weight = (const float*)d_in[2];  // [8,32,32,27]
    const float* bias   = (const float*)d_in[3];  // [8,32]
    float* out = (float*)d_out;
    char*  ws  = (char*)d_ws;

    condconv_prep<<<109, 256, 0, stream>>>(rw, weight, bias, ws);
    condconv_fused<<<dim3(8, 16, 8), 256, 0, stream>>>(
        x, ws + WF_OFF,
        (const float*)(ws + RWB_OFF), (const float*)(ws + RWS_OFF), out);
}